// Round 6
// baseline (461.586 us; speedup 1.0000x reference)
//
#include <hip/hip_runtime.h>
#include <math.h>

// ---------------- config ----------------
// JAX dropout RNG: jax_threefry_partitionable scheme (verified correct R1).
// Layer keys are compile-time constants (constexpr threefry of key(42) split).

#define Bsz 4
#define Nn  4096
#define Dd  64
#define TOT (Bsz*Nn*Dd)          // 1048576

typedef unsigned int u32;
typedef unsigned long long u64;
typedef short short8 __attribute__((ext_vector_type(8)));
typedef float f32x4 __attribute__((ext_vector_type(4)));

// ---------------- helpers ----------------
__device__ __forceinline__ unsigned short bf16_of(float x) {
  u32 u = __float_as_uint(x);
  u32 r = (u + 0x7FFFu + ((u >> 16) & 1u)) >> 16;   // RNE
  return (unsigned short)r;
}
__device__ __forceinline__ u32 pack2(float a, float b) {
  return (u32)bf16_of(a) | ((u32)bf16_of(b) << 16);
}
__device__ __forceinline__ void gll16(const void* g, void* l) {
  // async global->LDS, 16B/lane, dest = wave-uniform base + lane*16
  __builtin_amdgcn_global_load_lds((const __attribute__((address_space(1))) void*)g,
                                   (__attribute__((address_space(3))) void*)l, 16, 0, 0);
}

// Threefry-2x32 (exact JAX rotation/key schedule) — constexpr-able so the
// layer keys fold to literals at compile time.
struct kp { u32 a, b; };
__host__ __device__ constexpr kp tfp(u32 k0, u32 k1, u32 x0, u32 x1) {
  u32 ks2 = k0 ^ k1 ^ 0x1BD11BDAu;
  x0 += k0; x1 += k1;
#define TFR(r) { x0 += x1; x1 = (x1 << (r)) | (x1 >> (32 - (r))); x1 ^= x0; }
  TFR(13) TFR(15) TFR(26) TFR(6)
  x0 += k1; x1 += ks2 + 1u;
  TFR(17) TFR(29) TFR(16) TFR(24)
  x0 += ks2; x1 += k0 + 2u;
  TFR(13) TFR(15) TFR(26) TFR(6)
  x0 += k0; x1 += k1 + 3u;
  TFR(17) TFR(29) TFR(16) TFR(24)
  x0 += k1; x1 += ks2 + 4u;
  TFR(13) TFR(15) TFR(26) TFR(6)
  x0 += ks2; x1 += k0 + 5u;
#undef TFR
  return kp{x0, x1};
}
// split(key(42)) partitionable: key_i = threefry((0,42), (0,i))
constexpr kp KEY1 = tfp(0u, 42u, 0u, 0u);
constexpr kp KEY2 = tfp(0u, 42u, 0u, 1u);

// per-element dropout keep decision (exact JAX): fold-xor, top-23 bits -> [0,1)
__device__ __forceinline__ bool keep_elem(u32 ka, u32 kb, u32 f) {
  kp h = tfp(ka, kb, 0u, f);
  u32 bitsv = h.a ^ h.b;
  float u = __uint_as_float((bitsv >> 9) | 0x3F800000u) - 1.0f;
  return u < 0.8f;
}

// bit->bf16 expansion: byte (8 bits, tau-permuted at build time) -> 8 bf16 {0,1}
// element e <- byte bit tau(e), tau=(0,2,1,3,4,6,5,7) self-inverse.
__device__ __forceinline__ short8 expand_byte(u32 byte) {
  u32 lo = byte & 15u, hi = (byte >> 4) & 15u;
  u32 s0 = (lo * 0x00204081u) & 0x01010101u;
  u32 s1 = (hi * 0x00204081u) & 0x01010101u;
  union { u32 u[4]; short8 v; } r;
  r.u[0] = (s0 & 0x00010001u) * 0x3F80u;
  r.u[1] = ((s0 >> 8) & 0x00010001u) * 0x3F80u;
  r.u[2] = (s1 & 0x00010001u) * 0x3F80u;
  r.u[3] = ((s1 >> 8) & 0x00010001u) * 0x3F80u;
  return r.v;
}

// ---------------- kernel 1: adj -> bitmask + dinv ----------
__global__ __launch_bounds__(256) void k_bits(const int* __restrict__ adj,
                                              u64* __restrict__ bits,
                                              float* __restrict__ dinv) {
  int row = blockIdx.x;              // b*N + i
  int i = row & (Nn - 1);
  int lane = threadIdx.x & 63;
  int wv = threadIdx.x >> 6;
  __shared__ int cnts[4];
  int col0 = wv * 1024 + lane * 16;  // first of 16 columns this thread owns
  const int4* rp = (const int4*)(adj + (size_t)row * Nn + col0);
  int4 a0 = rp[0];
  int4 a1 = rp[1];
  int4 a2 = rp[2];
  int4 a3 = rp[3];
  // tau bit positions for e=0..7: 0,2,1,3,4,6,5,7
  u32 v = 0;
  v |= (a0.x != 0) ? (1u << 0) : 0u;
  v |= (a0.y != 0) ? (1u << 2) : 0u;
  v |= (a0.z != 0) ? (1u << 1) : 0u;
  v |= (a0.w != 0) ? (1u << 3) : 0u;
  v |= (a1.x != 0) ? (1u << 4) : 0u;
  v |= (a1.y != 0) ? (1u << 6) : 0u;
  v |= (a1.z != 0) ? (1u << 5) : 0u;
  v |= (a1.w != 0) ? (1u << 7) : 0u;
  v |= (a2.x != 0) ? (1u << 8) : 0u;
  v |= (a2.y != 0) ? (1u << 10) : 0u;
  v |= (a2.z != 0) ? (1u << 9) : 0u;
  v |= (a2.w != 0) ? (1u << 11) : 0u;
  v |= (a3.x != 0) ? (1u << 12) : 0u;
  v |= (a3.y != 0) ? (1u << 14) : 0u;
  v |= (a3.z != 0) ? (1u << 13) : 0u;
  v |= (a3.w != 0) ? (1u << 15) : 0u;
  if ((i >> 4) == (col0 >> 4)) {     // self-loop column lands in my 16
    int e = i & 15;
    int e7 = e & 7;
    int m = ((e7 ^ (e7 >> 1)) & 1);
    int bit = (e & 8) + (e7 ^ (m * 3));   // (e&8) + tau(e&7)
    v |= 1u << bit;
  }
  ((unsigned short*)bits)[(size_t)row * 256 + (size_t)(wv * 64 + lane)] =
      (unsigned short)v;
  int c = __popc(v);
  c += __shfl_down(c, 32, 64);
  c += __shfl_down(c, 16, 64);
  c += __shfl_down(c, 8, 64);
  c += __shfl_down(c, 4, 64);
  c += __shfl_down(c, 2, 64);
  c += __shfl_down(c, 1, 64);
  if (lane == 0) cnts[wv] = c;
  __syncthreads();
  if (threadIdx.x == 0) {
    int deg = cnts[0] + cnts[1] + cnts[2] + cnts[3];
    dinv[row] = (float)(1.0 / sqrt((double)deg));
  }
}

// ---------------- kernel 2: Yt = swizzled-transpose( dinv .* (X @ W) ) bf16 ----
// Layer-1 only (reads x directly). 64-row tile per block; MFMA 16x16x32 bf16.
__global__ __launch_bounds__(256) void k_xw(const float* __restrict__ X,
                                            const float* __restrict__ W,
                                            const float* __restrict__ dinv,
                                            unsigned short* __restrict__ Yt) {
  __shared__ __align__(16) unsigned short Xl[64][72];  // +8 pad: stride 144B
  __shared__ __align__(16) unsigned short Wt[64][72];  // W transposed [d][k]
  __shared__ float dl[64];
  int tid = threadIdx.x;
  int gi0 = blockIdx.x * 64;            // global row b*N + i
#pragma unroll
  for (int it = 0; it < 8; ++it) {      // X tile: 2048 bf16-pairs
    int p = it * 256 + tid;
    int r = p >> 5, c2 = (p & 31) * 2;
    const float* src = X + (size_t)(gi0 + r) * Dd + c2;
    *(u32*)&Xl[r][c2] = pack2(src[0], src[1]);
  }
#pragma unroll
  for (int it = 0; it < 16; ++it) {     // W: 4096 elems, transposed into Wt[d][k]
    int e = it * 256 + tid;
    int k = e >> 6, d = e & 63;
    Wt[d][k] = bf16_of(W[e]);
  }
  if (tid < 64) dl[tid] = dinv[gi0 + tid];
  __syncthreads();

  int lane = tid & 63, wv = tid >> 6;
  int q = lane >> 4, ln = lane & 15;
  f32x4 acc[4];
#pragma unroll
  for (int t = 0; t < 4; ++t) { acc[t][0]=0.f; acc[t][1]=0.f; acc[t][2]=0.f; acc[t][3]=0.f; }
#pragma unroll
  for (int ks = 0; ks < 2; ++ks) {
    short8 a = *(short8*)&Xl[wv * 16 + ln][ks * 32 + q * 8];
#pragma unroll
    for (int t = 0; t < 4; ++t) {
      short8 bfr = *(short8*)&Wt[t * 16 + ln][ks * 32 + q * 8];
      acc[t] = __builtin_amdgcn_mfma_f32_16x16x32_bf16(a, bfr, acc[t], 0, 0, 0);
    }
  }
  int b = gi0 >> 12;
  int i_in_b = gi0 & (Nn - 1);
#pragma unroll
  for (int t = 0; t < 4; ++t) {
    int d = t * 16 + ln;
    int j0 = i_in_b + wv * 16 + q * 4;  // node index of first of 4 rows
    unsigned short h[4];
#pragma unroll
    for (int r = 0; r < 4; ++r) h[r] = bf16_of(acc[t][r] * dl[wv * 16 + q * 4 + r]);
    int byte0 = (2 * j0) & 511;
    int blk = (2 * j0) >> 9;
    size_t off = ((size_t)b * 64 + d) * (Nn * 2) + ((size_t)blk << 9)
               + (size_t)(byte0 ^ ((d & 7) << 4));     // XOR swizzle per d
    uint2 st; st.x = (u32)h[0] | ((u32)h[1] << 16); st.y = (u32)h[2] | ((u32)h[3] << 16);
    *(uint2*)((char*)Yt + off) = st;
  }
}

// ---------------- kernel 3: mega = spmm(full K) + epilogue + next-layer XW ----
// One block per 32 output rows -> grid 512 = 2 blocks/CU (LDS ~78KB).
// 512 thr = 8 waves = kg(2) x dgrp(4). Each wave computes BOTH 16-row strips
// over its 16-d column group and K=2048: one bf ds_read feeds two MFMAs
// (per-strip A from adjacency bytes) -> LDS read amplification 1x (was 2x).
// K-groups reduced via LDS; epilogue (dinv*S+b, ELU, threefry dropout)
// in-register; then 32x64 H@W MFMA and swizzled bf16 Yt store for NEXT layer.
__global__ __launch_bounds__(512, 4) void k_mega(const u64* __restrict__ bits,
                                                 const unsigned short* __restrict__ Ytin,
                                                 const float* __restrict__ W,
                                                 const float* __restrict__ dinv,
                                                 const float* __restrict__ bias,
                                                 unsigned short* __restrict__ Ytout,
                                                 u32 ka, u32 kb) {
  __shared__ __align__(16) unsigned short Zt[2 * 64 * 256]; // 64 KB, [kg][d][512B]
  __shared__ __align__(16) unsigned short Xl[32][72];
  __shared__ __align__(16) unsigned short Wt[64][72];
  __shared__ float dl[32];
  __shared__ float bl[64];
  int tid = threadIdx.x;
  int lane = tid & 63, wv = tid >> 6;
  int kg = wv >> 2, sub = wv & 3;       // K-group (K=2048 each), d-group (16 d)
  int q = lane >> 4, ln = lane & 15;
  int gi0 = blockIdx.x * 32;            // flat row b*N + i
  int b = gi0 >> 12;

  // stage W (transposed, bf16), dinv, bias
#pragma unroll
  for (int it = 0; it < 8; ++it) {
    int e = it * 512 + tid;
    Wt[e & 63][e >> 6] = bf16_of(W[e]);
  }
  if (tid < 32) dl[tid] = dinv[gi0 + tid];
  else if (tid < 96) bl[tid - 32] = bias[tid - 32];

  const char* ytp = (const char*)Ytin + (size_t)b * 64 * (Nn * 2);
  const char* bitp0 = (const char*)bits + (size_t)(gi0 + ln) * 512 + (size_t)kg * 256;
  const char* bitp1 = (const char*)bits + (size_t)(gi0 + 16 + ln) * 512 + (size_t)kg * 256;

  f32x4 acc[2];
#pragma unroll
  for (int s = 0; s < 2; ++s) { acc[s][0]=0.f; acc[s][1]=0.f; acc[s][2]=0.f; acc[s][3]=0.f; }

  for (int it = 0; it < 8; ++it) {      // 8 phases x 256 K per K-group
    __syncthreads();                    // protect Zt from prev-phase readers
    int blk = kg * 8 + it;              // 512B block index in Yt row
#pragma unroll
    for (int qq = 0; qq < 8; ++qq) {    // stage 8 KB per wave -> 32 KB per kg
      int c = sub * 8 + qq;
      int d = c * 2 + (lane >> 5);
      const char* g = ytp + (size_t)d * (Nn * 2) + ((size_t)blk << 9)
                    + (size_t)(lane & 31) * 16;
      gll16(g, (char*)Zt + (size_t)kg * 32768 + (size_t)c * 1024);
    }
    // adjacency bits for BOTH strips, this 256-K chunk: 2 x 32B into registers
    uint4 w00 = *(const uint4*)(bitp0 + it * 32);
    uint4 w01 = *(const uint4*)(bitp0 + it * 32 + 16);
    uint4 w10 = *(const uint4*)(bitp1 + it * 32);
    uint4 w11 = *(const uint4*)(bitp1 + it * 32 + 16);
    __builtin_amdgcn_s_waitcnt(0);
    __syncthreads();
    u64 wdv0[4], wdv1[4];
    wdv0[0] = (u64)w00.x | ((u64)w00.y << 32);
    wdv0[1] = (u64)w00.z | ((u64)w00.w << 32);
    wdv0[2] = (u64)w01.x | ((u64)w01.y << 32);
    wdv0[3] = (u64)w01.z | ((u64)w01.w << 32);
    wdv1[0] = (u64)w10.x | ((u64)w10.y << 32);
    wdv1[1] = (u64)w10.z | ((u64)w10.w << 32);
    wdv1[2] = (u64)w11.x | ((u64)w11.y << 32);
    wdv1[3] = (u64)w11.z | ((u64)w11.w << 32);
#pragma unroll
    for (int kk = 0; kk < 8; ++kk) {
      int d = sub * 16 + ln;
      int off = kg * 32768 + d * 512 + ((kk * 64 + q * 16) ^ ((d & 7) << 4));
      short8 bf = *(short8*)((char*)Zt + off);
      int sh = 8 * (4 * (kk & 1) + q);
      u32 by0 = (u32)(wdv0[kk >> 1] >> sh) & 0xFFu;
      u32 by1 = (u32)(wdv1[kk >> 1] >> sh) & 0xFFu;
      short8 a0 = expand_byte(by0);
      short8 a1 = expand_byte(by1);
      acc[0] = __builtin_amdgcn_mfma_f32_16x16x32_bf16(a0, bf, acc[0], 0, 0, 0);
      acc[1] = __builtin_amdgcn_mfma_f32_16x16x32_bf16(a1, bf, acc[1], 0, 0, 0);
    }
  }

  // ---- cross-K-group reduction via LDS (reuse Zt as [32][68] f32) ----
  __syncthreads();                      // last compute done; Zt reusable
  float* red = (float*)Zt;
  if (kg == 1) {
#pragma unroll
    for (int s = 0; s < 2; ++s) {
      int d = sub * 16 + ln;
#pragma unroll
      for (int r = 0; r < 4; ++r)
        red[(s * 16 + q * 4 + r) * 68 + d] = acc[s][r];
    }
  }
  __syncthreads();
  if (kg == 0) {
#pragma unroll
    for (int s = 0; s < 2; ++s) {
      int d = sub * 16 + ln;
#pragma unroll
      for (int r = 0; r < 4; ++r)
        red[(s * 16 + q * 4 + r) * 68 + d] += acc[s][r];
    }
  }
  __syncthreads();

  // ---- epilogue: all 8 waves, 4 elems/thread ----
  {
    int row = tid >> 4, d0 = (tid & 15) * 4;
    float dv = dl[row];
    f32x4 v0 = *(f32x4*)&red[row * 68 + d0];
    float h2[4];
#pragma unroll
    for (int j = 0; j < 4; ++j) {
      float s = v0[j] * dv + bl[d0 + j];
      float el = s > 0.f ? s : expm1f(s);
      u32 f = (u32)((gi0 + row) * 64 + d0 + j);
      h2[j] = keep_elem(ka, kb, f) ? el * 1.25f : 0.f;  // /0.8 == *1.25
    }
    uint2 st; st.x = pack2(h2[0], h2[1]); st.y = pack2(h2[2], h2[3]);
    *(uint2*)&Xl[row][d0] = st;
  }
  __syncthreads();

  // ---- next-layer XW: 8 waves = strip2(2) x th(4), each 16 rows x 16 d ----
  {
    int strip2 = wv & 1, th = wv >> 1;
    f32x4 a2;
    a2[0]=0.f; a2[1]=0.f; a2[2]=0.f; a2[3]=0.f;
#pragma unroll
    for (int ks = 0; ks < 2; ++ks) {
      short8 a = *(short8*)&Xl[strip2 * 16 + ln][ks * 32 + q * 8];
      short8 bfr = *(short8*)&Wt[th * 16 + ln][ks * 32 + q * 8];
      a2 = __builtin_amdgcn_mfma_f32_16x16x32_bf16(a, bfr, a2, 0, 0, 0);
    }
    int i_in_b = gi0 & (Nn - 1);
    int d = th * 16 + ln;
    int j0 = i_in_b + strip2 * 16 + q * 4;
    unsigned short h[4];
#pragma unroll
    for (int r = 0; r < 4; ++r)
      h[r] = bf16_of(a2[r] * dl[strip2 * 16 + q * 4 + r]);
    int byte0 = (2 * j0) & 511;
    int blkk = (2 * j0) >> 9;
    size_t off = ((size_t)b * 64 + d) * (Nn * 2) + ((size_t)blkk << 9)
               + (size_t)(byte0 ^ ((d & 7) << 4));
    uint2 st; st.x = (u32)h[0] | ((u32)h[1] << 16); st.y = (u32)h[2] | ((u32)h[3] << 16);
    *(uint2*)((char*)Ytout + off) = st;
  }
}

// ---------------- kernel 4: final = spmm(full K) + dinv*S + bias -> out ------
__global__ __launch_bounds__(512, 4) void k_fin(const u64* __restrict__ bits,
                                                const unsigned short* __restrict__ Ytin,
                                                const float* __restrict__ dinv,
                                                const float* __restrict__ bias,
                                                float* __restrict__ out) {
  __shared__ __align__(16) unsigned short Zt[2 * 64 * 256]; // 64 KB
  __shared__ float dl[32];
  __shared__ float bl[64];
  int tid = threadIdx.x;
  int lane = tid & 63, wv = tid >> 6;
  int kg = wv >> 2, sub = wv & 3;
  int q = lane >> 4, ln = lane & 15;
  int gi0 = blockIdx.x * 32;
  int b = gi0 >> 12;

  if (tid < 32) dl[tid] = dinv[gi0 + tid];
  else if (tid < 96) bl[tid - 32] = bias[tid - 32];

  const char* ytp = (const char*)Ytin + (size_t)b * 64 * (Nn * 2);
  const char* bitp0 = (const char*)bits + (size_t)(gi0 + ln) * 512 + (size_t)kg * 256;
  const char* bitp1 = (const char*)bits + (size_t)(gi0 + 16 + ln) * 512 + (size_t)kg * 256;

  f32x4 acc[2];
#pragma unroll
  for (int s = 0; s < 2; ++s) { acc[s][0]=0.f; acc[s][1]=0.f; acc[s][2]=0.f; acc[s][3]=0.f; }

  for (int it = 0; it < 8; ++it) {
    __syncthreads();
    int blk = kg * 8 + it;
#pragma unroll
    for (int qq = 0; qq < 8; ++qq) {
      int c = sub * 8 + qq;
      int d = c * 2 + (lane >> 5);
      const char* g = ytp + (size_t)d * (Nn * 2) + ((size_t)blk << 9)
                    + (size_t)(lane & 31) * 16;
      gll16(g, (char*)Zt + (size_t)kg * 32768 + (size_t)c * 1024);
    }
    uint4 w00 = *(const uint4*)(bitp0 + it * 32);
    uint4 w01 = *(const uint4*)(bitp0 + it * 32 + 16);
    uint4 w10 = *(const uint4*)(bitp1 + it * 32);
    uint4 w11 = *(const uint4*)(bitp1 + it * 32 + 16);
    __builtin_amdgcn_s_waitcnt(0);
    __syncthreads();
    u64 wdv0[4], wdv1[4];
    wdv0[0] = (u64)w00.x | ((u64)w00.y << 32);
    wdv0[1] = (u64)w00.z | ((u64)w00.w << 32);
    wdv0[2] = (u64)w01.x | ((u64)w01.y << 32);
    wdv0[3] = (u64)w01.z | ((u64)w01.w << 32);
    wdv1[0] = (u64)w10.x | ((u64)w10.y << 32);
    wdv1[1] = (u64)w10.z | ((u64)w10.w << 32);
    wdv1[2] = (u64)w11.x | ((u64)w11.y << 32);
    wdv1[3] = (u64)w11.z | ((u64)w11.w << 32);
#pragma unroll
    for (int kk = 0; kk < 8; ++kk) {
      int d = sub * 16 + ln;
      int off = kg * 32768 + d * 512 + ((kk * 64 + q * 16) ^ ((d & 7) << 4));
      short8 bf = *(short8*)((char*)Zt + off);
      int sh = 8 * (4 * (kk & 1) + q);
      u32 by0 = (u32)(wdv0[kk >> 1] >> sh) & 0xFFu;
      u32 by1 = (u32)(wdv1[kk >> 1] >> sh) & 0xFFu;
      short8 a0 = expand_byte(by0);
      short8 a1 = expand_byte(by1);
      acc[0] = __builtin_amdgcn_mfma_f32_16x16x32_bf16(a0, bf, acc[0], 0, 0, 0);
      acc[1] = __builtin_amdgcn_mfma_f32_16x16x32_bf16(a1, bf, acc[1], 0, 0, 0);
    }
  }

  __syncthreads();
  float* red = (float*)Zt;
  if (kg == 1) {
#pragma unroll
    for (int s = 0; s < 2; ++s) {
      int d = sub * 16 + ln;
#pragma unroll
      for (int r = 0; r < 4; ++r)
        red[(s * 16 + q * 4 + r) * 68 + d] = acc[s][r];
    }
  }
  __syncthreads();
  if (kg == 0) {
#pragma unroll
    for (int s = 0; s < 2; ++s) {
      int d = sub * 16 + ln;
#pragma unroll
      for (int r = 0; r < 4; ++r)
        red[(s * 16 + q * 4 + r) * 68 + d] += acc[s][r];
    }
  }
  __syncthreads();

  {
    int row = tid >> 4, d0 = (tid & 15) * 4;
    float dv = dl[row];
    f32x4 v0 = *(f32x4*)&red[row * 68 + d0];
    float4 o;
    o.x = v0[0] * dv + bl[d0 + 0];
    o.y = v0[1] * dv + bl[d0 + 1];
    o.z = v0[2] * dv + bl[d0 + 2];
    o.w = v0[3] * dv + bl[d0 + 3];
    *(float4*)(out + (size_t)(gi0 + row) * 64 + d0) = o;
  }
}

// ---------------- launch ----------------
extern "C" void kernel_launch(void* const* d_in, const int* in_sizes, int n_in,
                              void* d_out, int out_size, void* d_ws, size_t ws_size,
                              hipStream_t stream) {
  const float* x  = (const float*)d_in[0];
  const int*   adj= (const int*)d_in[1];
  const float* W1 = (const float*)d_in[2];
  const float* b1 = (const float*)d_in[3];
  const float* W2 = (const float*)d_in[4];
  const float* b2 = (const float*)d_in[5];
  const float* W3 = (const float*)d_in[6];
  const float* b3 = (const float*)d_in[7];
  float* out = (float*)d_out;
  char* ws = (char*)d_ws;

  u64*            bits = (u64*)(ws);                         // 8,388,608 B
  float*          dinv = (float*)(ws + 8388608);             //    65,536 B
  unsigned short* YtA  = (unsigned short*)(ws + 8454144);    // 2,097,152 B
  unsigned short* YtB  = (unsigned short*)(ws + 10551296);   // 2,097,152 B

  k_bits<<<Bsz * Nn, 256, 0, stream>>>(adj, bits, dinv);

  // layer 1 XW
  k_xw<<<(Bsz * Nn) / 64, 256, 0, stream>>>(x, W1, dinv, YtA);
  // layer 1 aggregate + epilogue + layer 2 XW
  k_mega<<<(Bsz * Nn) / 32, 512, 0, stream>>>(bits, YtA, W2, dinv, b1, YtB,
                                              KEY1.a, KEY1.b);
  // layer 2 aggregate + epilogue + layer 3 XW
  k_mega<<<(Bsz * Nn) / 32, 512, 0, stream>>>(bits, YtB, W3, dinv, b2, YtA,
                                              KEY2.a, KEY2.b);
  // layer 3 aggregate + bias -> out
  k_fin<<<(Bsz * Nn) / 32, 512, 0, stream>>>(bits, YtA, dinv, b3, out);
}

// Round 7
// 437.757 us; speedup vs baseline: 1.0544x; 1.0544x over previous
//
#include <hip/hip_runtime.h>
#include <math.h>

// ---------------- config ----------------
// JAX dropout RNG: jax_threefry_partitionable scheme (verified correct R1).
// Layer keys are compile-time constants (constexpr threefry of key(42) split).

#define Bsz 4
#define Nn  4096
#define Dd  64
#define TOT (Bsz*Nn*Dd)          // 1048576

typedef unsigned int u32;
typedef unsigned long long u64;
typedef short short8 __attribute__((ext_vector_type(8)));
typedef float f32x4 __attribute__((ext_vector_type(4)));

// ---------------- helpers ----------------
__device__ __forceinline__ unsigned short bf16_of(float x) {
  u32 u = __float_as_uint(x);
  u32 r = (u + 0x7FFFu + ((u >> 16) & 1u)) >> 16;   // RNE
  return (unsigned short)r;
}
__device__ __forceinline__ u32 pack2(float a, float b) {
  return (u32)bf16_of(a) | ((u32)bf16_of(b) << 16);
}
__device__ __forceinline__ void gll16(const void* g, void* l) {
  // async global->LDS, 16B/lane, dest = wave-uniform base + lane*16
  __builtin_amdgcn_global_load_lds((const __attribute__((address_space(1))) void*)g,
                                   (__attribute__((address_space(3))) void*)l, 16, 0, 0);
}

// Threefry-2x32 (exact JAX rotation/key schedule) — constexpr-able so the
// layer keys fold to literals at compile time.
struct kp { u32 a, b; };
__host__ __device__ constexpr kp tfp(u32 k0, u32 k1, u32 x0, u32 x1) {
  u32 ks2 = k0 ^ k1 ^ 0x1BD11BDAu;
  x0 += k0; x1 += k1;
#define TFR(r) { x0 += x1; x1 = (x1 << (r)) | (x1 >> (32 - (r))); x1 ^= x0; }
  TFR(13) TFR(15) TFR(26) TFR(6)
  x0 += k1; x1 += ks2 + 1u;
  TFR(17) TFR(29) TFR(16) TFR(24)
  x0 += ks2; x1 += k0 + 2u;
  TFR(13) TFR(15) TFR(26) TFR(6)
  x0 += k0; x1 += k1 + 3u;
  TFR(17) TFR(29) TFR(16) TFR(24)
  x0 += k1; x1 += ks2 + 4u;
  TFR(13) TFR(15) TFR(26) TFR(6)
  x0 += ks2; x1 += k0 + 5u;
#undef TFR
  return kp{x0, x1};
}
// split(key(42)) partitionable: key_i = threefry((0,42), (0,i))
constexpr kp KEY1 = tfp(0u, 42u, 0u, 0u);
constexpr kp KEY2 = tfp(0u, 42u, 0u, 1u);

// per-element dropout keep decision (exact JAX): fold-xor, top-23 bits -> [0,1)
__device__ __forceinline__ bool keep_elem(u32 ka, u32 kb, u32 f) {
  kp h = tfp(ka, kb, 0u, f);
  u32 bitsv = h.a ^ h.b;
  float u = __uint_as_float((bitsv >> 9) | 0x3F800000u) - 1.0f;
  return u < 0.8f;
}

// bit->bf16 expansion: byte (8 bits, tau-permuted at build time) -> 8 bf16 {0,1}
// element e <- byte bit tau(e), tau=(0,2,1,3,4,6,5,7) self-inverse.
__device__ __forceinline__ short8 expand_byte(u32 byte) {
  u32 lo = byte & 15u, hi = (byte >> 4) & 15u;
  u32 s0 = (lo * 0x00204081u) & 0x01010101u;
  u32 s1 = (hi * 0x00204081u) & 0x01010101u;
  union { u32 u[4]; short8 v; } r;
  r.u[0] = (s0 & 0x00010001u) * 0x3F80u;
  r.u[1] = ((s0 >> 8) & 0x00010001u) * 0x3F80u;
  r.u[2] = (s1 & 0x00010001u) * 0x3F80u;
  r.u[3] = ((s1 >> 8) & 0x00010001u) * 0x3F80u;
  return r.v;
}

// ---------------- kernel 1: adj -> bitmask + dinv ----------
__global__ __launch_bounds__(256) void k_bits(const int* __restrict__ adj,
                                              u64* __restrict__ bits,
                                              float* __restrict__ dinv) {
  int row = blockIdx.x;              // b*N + i
  int i = row & (Nn - 1);
  int lane = threadIdx.x & 63;
  int wv = threadIdx.x >> 6;
  __shared__ int cnts[4];
  int col0 = wv * 1024 + lane * 16;  // first of 16 columns this thread owns
  const int4* rp = (const int4*)(adj + (size_t)row * Nn + col0);
  int4 a0 = rp[0];
  int4 a1 = rp[1];
  int4 a2 = rp[2];
  int4 a3 = rp[3];
  // tau bit positions for e=0..7: 0,2,1,3,4,6,5,7
  u32 v = 0;
  v |= (a0.x != 0) ? (1u << 0) : 0u;
  v |= (a0.y != 0) ? (1u << 2) : 0u;
  v |= (a0.z != 0) ? (1u << 1) : 0u;
  v |= (a0.w != 0) ? (1u << 3) : 0u;
  v |= (a1.x != 0) ? (1u << 4) : 0u;
  v |= (a1.y != 0) ? (1u << 6) : 0u;
  v |= (a1.z != 0) ? (1u << 5) : 0u;
  v |= (a1.w != 0) ? (1u << 7) : 0u;
  v |= (a2.x != 0) ? (1u << 8) : 0u;
  v |= (a2.y != 0) ? (1u << 10) : 0u;
  v |= (a2.z != 0) ? (1u << 9) : 0u;
  v |= (a2.w != 0) ? (1u << 11) : 0u;
  v |= (a3.x != 0) ? (1u << 12) : 0u;
  v |= (a3.y != 0) ? (1u << 14) : 0u;
  v |= (a3.z != 0) ? (1u << 13) : 0u;
  v |= (a3.w != 0) ? (1u << 15) : 0u;
  if ((i >> 4) == (col0 >> 4)) {     // self-loop column lands in my 16
    int e = i & 15;
    int e7 = e & 7;
    int m = ((e7 ^ (e7 >> 1)) & 1);
    int bit = (e & 8) + (e7 ^ (m * 3));   // (e&8) + tau(e&7)
    v |= 1u << bit;
  }
  ((unsigned short*)bits)[(size_t)row * 256 + (size_t)(wv * 64 + lane)] =
      (unsigned short)v;
  int c = __popc(v);
  c += __shfl_down(c, 32, 64);
  c += __shfl_down(c, 16, 64);
  c += __shfl_down(c, 8, 64);
  c += __shfl_down(c, 4, 64);
  c += __shfl_down(c, 2, 64);
  c += __shfl_down(c, 1, 64);
  if (lane == 0) cnts[wv] = c;
  __syncthreads();
  if (threadIdx.x == 0) {
    int deg = cnts[0] + cnts[1] + cnts[2] + cnts[3];
    dinv[row] = (float)(1.0 / sqrt((double)deg));
  }
}

// ---------------- kernel 2: Yt = swizzled-transpose( dinv .* (X @ W) ) bf16 ----
// Layer-1 only (reads x directly). 64-row tile per block; MFMA 16x16x32 bf16.
__global__ __launch_bounds__(256) void k_xw(const float* __restrict__ X,
                                            const float* __restrict__ W,
                                            const float* __restrict__ dinv,
                                            unsigned short* __restrict__ Yt) {
  __shared__ __align__(16) unsigned short Xl[64][72];  // +8 pad: stride 144B
  __shared__ __align__(16) unsigned short Wt[64][72];  // W transposed [d][k]
  __shared__ float dl[64];
  int tid = threadIdx.x;
  int gi0 = blockIdx.x * 64;            // global row b*N + i
#pragma unroll
  for (int it = 0; it < 8; ++it) {      // X tile: 2048 bf16-pairs
    int p = it * 256 + tid;
    int r = p >> 5, c2 = (p & 31) * 2;
    const float* src = X + (size_t)(gi0 + r) * Dd + c2;
    *(u32*)&Xl[r][c2] = pack2(src[0], src[1]);
  }
#pragma unroll
  for (int it = 0; it < 16; ++it) {     // W: 4096 elems, transposed into Wt[d][k]
    int e = it * 256 + tid;
    int k = e >> 6, d = e & 63;
    Wt[d][k] = bf16_of(W[e]);
  }
  if (tid < 64) dl[tid] = dinv[gi0 + tid];
  __syncthreads();

  int lane = tid & 63, wv = tid >> 6;
  int q = lane >> 4, ln = lane & 15;
  f32x4 acc[4];
#pragma unroll
  for (int t = 0; t < 4; ++t) { acc[t][0]=0.f; acc[t][1]=0.f; acc[t][2]=0.f; acc[t][3]=0.f; }
#pragma unroll
  for (int ks = 0; ks < 2; ++ks) {
    short8 a = *(short8*)&Xl[wv * 16 + ln][ks * 32 + q * 8];
#pragma unroll
    for (int t = 0; t < 4; ++t) {
      short8 bfr = *(short8*)&Wt[t * 16 + ln][ks * 32 + q * 8];
      acc[t] = __builtin_amdgcn_mfma_f32_16x16x32_bf16(a, bfr, acc[t], 0, 0, 0);
    }
  }
  int b = gi0 >> 12;
  int i_in_b = gi0 & (Nn - 1);
#pragma unroll
  for (int t = 0; t < 4; ++t) {
    int d = t * 16 + ln;
    int j0 = i_in_b + wv * 16 + q * 4;  // node index of first of 4 rows
    unsigned short h[4];
#pragma unroll
    for (int r = 0; r < 4; ++r) h[r] = bf16_of(acc[t][r] * dl[wv * 16 + q * 4 + r]);
    int byte0 = (2 * j0) & 511;
    int blk = (2 * j0) >> 9;
    size_t off = ((size_t)b * 64 + d) * (Nn * 2) + ((size_t)blk << 9)
               + (size_t)(byte0 ^ ((d & 7) << 4));     // XOR swizzle per d
    uint2 st; st.x = (u32)h[0] | ((u32)h[1] << 16); st.y = (u32)h[2] | ((u32)h[3] << 16);
    *(uint2*)((char*)Yt + off) = st;
  }
}

// ---------------- kernel 3: mega = spmm(full K) + epilogue + next-layer XW ----
// One block per 32 output rows -> grid 512 = 2 blocks/CU (LDS ~78KB).
// 512 thr = 8 waves = kg(2) x row-strip(2) x d-group(2). Each wave accumulates
// 16 rows x 32 d over K=2048; K-groups reduced via LDS; epilogue (dinv*S+b,
// ELU, threefry dropout) in-register; then 32x64 H@W MFMA and swizzled bf16
// Yt store for the NEXT layer. Cross-block overlap hides per-phase drains.
__global__ __launch_bounds__(512, 4) void k_mega(const u64* __restrict__ bits,
                                                 const unsigned short* __restrict__ Ytin,
                                                 const float* __restrict__ W,
                                                 const float* __restrict__ dinv,
                                                 const float* __restrict__ bias,
                                                 unsigned short* __restrict__ Ytout,
                                                 u32 ka, u32 kb) {
  __shared__ __align__(16) unsigned short Zt[2 * 64 * 256]; // 64 KB, [kg][d][512B]
  __shared__ __align__(16) unsigned short Xl[32][72];
  __shared__ __align__(16) unsigned short Wt[64][72];
  __shared__ float dl[32];
  __shared__ float bl[64];
  int tid = threadIdx.x;
  int lane = tid & 63, wv = tid >> 6;
  int kg = wv >> 2, sub = wv & 3;       // K-group (K=2048 each), sub-wave
  int strip = sub >> 1, dgrp = sub & 1; // row-strip (16 rows), d-group (32 d)
  int q = lane >> 4, ln = lane & 15;
  int gi0 = blockIdx.x * 32;            // flat row b*N + i
  int b = gi0 >> 12;

  // stage W (transposed, bf16), dinv, bias
#pragma unroll
  for (int it = 0; it < 8; ++it) {
    int e = it * 512 + tid;
    Wt[e & 63][e >> 6] = bf16_of(W[e]);
  }
  if (tid < 32) dl[tid] = dinv[gi0 + tid];
  else if (tid < 96) bl[tid - 32] = bias[tid - 32];

  const char* ytp = (const char*)Ytin + (size_t)b * 64 * (Nn * 2);
  const char* bitp = (const char*)bits + (size_t)(gi0 + strip * 16 + ln) * 512
                   + (size_t)kg * 256;

  f32x4 acc[2];
#pragma unroll
  for (int t = 0; t < 2; ++t) { acc[t][0]=0.f; acc[t][1]=0.f; acc[t][2]=0.f; acc[t][3]=0.f; }

  for (int it = 0; it < 8; ++it) {      // 8 phases x 256 K per K-group
    __syncthreads();                    // protect Zt from prev-phase readers
    int blk = kg * 8 + it;              // 512B block index in Yt row
#pragma unroll
    for (int qq = 0; qq < 8; ++qq) {    // stage 8 KB per wave -> 32 KB per kg
      int c = sub * 8 + qq;
      int d = c * 2 + (lane >> 5);
      const char* g = ytp + (size_t)d * (Nn * 2) + ((size_t)blk << 9)
                    + (size_t)(lane & 31) * 16;
      gll16(g, (char*)Zt + (size_t)kg * 32768 + (size_t)c * 1024);
    }
    // adjacency bits for my row, this 256-K chunk: 32B into registers
    uint4 w0 = *(const uint4*)(bitp + it * 32);
    uint4 w1 = *(const uint4*)(bitp + it * 32 + 16);
    __builtin_amdgcn_s_waitcnt(0);
    __syncthreads();
    u64 wdv[4];
    wdv[0] = (u64)w0.x | ((u64)w0.y << 32);
    wdv[1] = (u64)w0.z | ((u64)w0.w << 32);
    wdv[2] = (u64)w1.x | ((u64)w1.y << 32);
    wdv[3] = (u64)w1.z | ((u64)w1.w << 32);
#pragma unroll
    for (int kk = 0; kk < 8; ++kk) {
      short8 bf[2];
#pragma unroll
      for (int t = 0; t < 2; ++t) {
        int d = (dgrp * 2 + t) * 16 + ln;
        int off = kg * 32768 + d * 512 + ((kk * 64 + q * 16) ^ ((d & 7) << 4));
        bf[t] = *(short8*)((char*)Zt + off);
      }
      u32 byte = (u32)(wdv[kk >> 1] >> (8 * (4 * (kk & 1) + q))) & 0xFFu;
      short8 af = expand_byte(byte);
#pragma unroll
      for (int t = 0; t < 2; ++t)
        acc[t] = __builtin_amdgcn_mfma_f32_16x16x32_bf16(af, bf[t], acc[t], 0, 0, 0);
    }
  }

  // ---- cross-K-group reduction via LDS (reuse Zt as [32][68] f32) ----
  __syncthreads();                      // last compute done; Zt reusable
  float* red = (float*)Zt;
  if (kg == 1) {
#pragma unroll
    for (int t = 0; t < 2; ++t) {
      int d = (dgrp * 2 + t) * 16 + ln;
#pragma unroll
      for (int r = 0; r < 4; ++r)
        red[(strip * 16 + q * 4 + r) * 68 + d] = acc[t][r];
    }
  }
  __syncthreads();
  if (kg == 0) {
#pragma unroll
    for (int t = 0; t < 2; ++t) {
      int d = (dgrp * 2 + t) * 16 + ln;
#pragma unroll
      for (int r = 0; r < 4; ++r)
        red[(strip * 16 + q * 4 + r) * 68 + d] += acc[t][r];
    }
  }
  __syncthreads();

  // ---- epilogue: all 8 waves, 4 elems/thread ----
  {
    int row = tid >> 4, d0 = (tid & 15) * 4;
    float dv = dl[row];
    f32x4 v0 = *(f32x4*)&red[row * 68 + d0];
    u32 pk0, pk1;
    {
      float h2[4];
#pragma unroll
      for (int j = 0; j < 4; ++j) {
        float s = v0[j] * dv + bl[d0 + j];
        float el = s > 0.f ? s : expm1f(s);
        u32 f = (u32)((gi0 + row) * 64 + d0 + j);
        h2[j] = keep_elem(ka, kb, f) ? el * 1.25f : 0.f;  // /0.8 == *1.25
      }
      pk0 = pack2(h2[0], h2[1]);
      pk1 = pack2(h2[2], h2[3]);
    }
    uint2 st; st.x = pk0; st.y = pk1;
    *(uint2*)&Xl[row][d0] = st;
  }
  __syncthreads();

  // ---- next-layer XW: 8 waves = strip2(2) x th(4), each 16 rows x 16 d ----
  {
    int strip2 = wv & 1, th = wv >> 1;
    f32x4 a2;
    a2[0]=0.f; a2[1]=0.f; a2[2]=0.f; a2[3]=0.f;
#pragma unroll
    for (int ks = 0; ks < 2; ++ks) {
      short8 a = *(short8*)&Xl[strip2 * 16 + ln][ks * 32 + q * 8];
      short8 bfr = *(short8*)&Wt[th * 16 + ln][ks * 32 + q * 8];
      a2 = __builtin_amdgcn_mfma_f32_16x16x32_bf16(a, bfr, a2, 0, 0, 0);
    }
    int i_in_b = gi0 & (Nn - 1);
    int d = th * 16 + ln;
    int j0 = i_in_b + strip2 * 16 + q * 4;
    unsigned short h[4];
#pragma unroll
    for (int r = 0; r < 4; ++r)
      h[r] = bf16_of(a2[r] * dl[strip2 * 16 + q * 4 + r]);
    int byte0 = (2 * j0) & 511;
    int blkk = (2 * j0) >> 9;
    size_t off = ((size_t)b * 64 + d) * (Nn * 2) + ((size_t)blkk << 9)
               + (size_t)(byte0 ^ ((d & 7) << 4));
    uint2 st; st.x = (u32)h[0] | ((u32)h[1] << 16); st.y = (u32)h[2] | ((u32)h[3] << 16);
    *(uint2*)((char*)Ytout + off) = st;
  }
}

// ---------------- kernel 4: final = spmm(full K) + dinv*S + bias -> out ------
__global__ __launch_bounds__(512, 4) void k_fin(const u64* __restrict__ bits,
                                                const unsigned short* __restrict__ Ytin,
                                                const float* __restrict__ dinv,
                                                const float* __restrict__ bias,
                                                float* __restrict__ out) {
  __shared__ __align__(16) unsigned short Zt[2 * 64 * 256]; // 64 KB
  __shared__ float dl[32];
  __shared__ float bl[64];
  int tid = threadIdx.x;
  int lane = tid & 63, wv = tid >> 6;
  int kg = wv >> 2, sub = wv & 3;
  int strip = sub >> 1, dgrp = sub & 1;
  int q = lane >> 4, ln = lane & 15;
  int gi0 = blockIdx.x * 32;
  int b = gi0 >> 12;

  if (tid < 32) dl[tid] = dinv[gi0 + tid];
  else if (tid < 96) bl[tid - 32] = bias[tid - 32];

  const char* ytp = (const char*)Ytin + (size_t)b * 64 * (Nn * 2);
  const char* bitp = (const char*)bits + (size_t)(gi0 + strip * 16 + ln) * 512
                   + (size_t)kg * 256;

  f32x4 acc[2];
#pragma unroll
  for (int t = 0; t < 2; ++t) { acc[t][0]=0.f; acc[t][1]=0.f; acc[t][2]=0.f; acc[t][3]=0.f; }

  for (int it = 0; it < 8; ++it) {
    __syncthreads();
    int blk = kg * 8 + it;
#pragma unroll
    for (int qq = 0; qq < 8; ++qq) {
      int c = sub * 8 + qq;
      int d = c * 2 + (lane >> 5);
      const char* g = ytp + (size_t)d * (Nn * 2) + ((size_t)blk << 9)
                    + (size_t)(lane & 31) * 16;
      gll16(g, (char*)Zt + (size_t)kg * 32768 + (size_t)c * 1024);
    }
    uint4 w0 = *(const uint4*)(bitp + it * 32);
    uint4 w1 = *(const uint4*)(bitp + it * 32 + 16);
    __builtin_amdgcn_s_waitcnt(0);
    __syncthreads();
    u64 wdv[4];
    wdv[0] = (u64)w0.x | ((u64)w0.y << 32);
    wdv[1] = (u64)w0.z | ((u64)w0.w << 32);
    wdv[2] = (u64)w1.x | ((u64)w1.y << 32);
    wdv[3] = (u64)w1.z | ((u64)w1.w << 32);
#pragma unroll
    for (int kk = 0; kk < 8; ++kk) {
      short8 bf[2];
#pragma unroll
      for (int t = 0; t < 2; ++t) {
        int d = (dgrp * 2 + t) * 16 + ln;
        int off = kg * 32768 + d * 512 + ((kk * 64 + q * 16) ^ ((d & 7) << 4));
        bf[t] = *(short8*)((char*)Zt + off);
      }
      u32 byte = (u32)(wdv[kk >> 1] >> (8 * (4 * (kk & 1) + q))) & 0xFFu;
      short8 af = expand_byte(byte);
#pragma unroll
      for (int t = 0; t < 2; ++t)
        acc[t] = __builtin_amdgcn_mfma_f32_16x16x32_bf16(af, bf[t], acc[t], 0, 0, 0);
    }
  }

  __syncthreads();
  float* red = (float*)Zt;
  if (kg == 1) {
#pragma unroll
    for (int t = 0; t < 2; ++t) {
      int d = (dgrp * 2 + t) * 16 + ln;
#pragma unroll
      for (int r = 0; r < 4; ++r)
        red[(strip * 16 + q * 4 + r) * 68 + d] = acc[t][r];
    }
  }
  __syncthreads();
  if (kg == 0) {
#pragma unroll
    for (int t = 0; t < 2; ++t) {
      int d = (dgrp * 2 + t) * 16 + ln;
#pragma unroll
      for (int r = 0; r < 4; ++r) {
        int rl = strip * 16 + q * 4 + r;
        float s = (red[rl * 68 + d] + acc[t][r]) * dl[rl] + bl[d];
        out[(size_t)(gi0 + rl) * 64 + d] = s;
      }
    }
  }
}

// ---------------- launch ----------------
extern "C" void kernel_launch(void* const* d_in, const int* in_sizes, int n_in,
                              void* d_out, int out_size, void* d_ws, size_t ws_size,
                              hipStream_t stream) {
  const float* x  = (const float*)d_in[0];
  const int*   adj= (const int*)d_in[1];
  const float* W1 = (const float*)d_in[2];
  const float* b1 = (const float*)d_in[3];
  const float* W2 = (const float*)d_in[4];
  const float* b2 = (const float*)d_in[5];
  const float* W3 = (const float*)d_in[6];
  const float* b3 = (const float*)d_in[7];
  float* out = (float*)d_out;
  char* ws = (char*)d_ws;

  u64*            bits = (u64*)(ws);                         // 8,388,608 B
  float*          dinv = (float*)(ws + 8388608);             //    65,536 B
  unsigned short* YtA  = (unsigned short*)(ws + 8454144);    // 2,097,152 B
  unsigned short* YtB  = (unsigned short*)(ws + 10551296);   // 2,097,152 B

  k_bits<<<Bsz * Nn, 256, 0, stream>>>(adj, bits, dinv);

  // layer 1 XW
  k_xw<<<(Bsz * Nn) / 64, 256, 0, stream>>>(x, W1, dinv, YtA);
  // layer 1 aggregate + epilogue + layer 2 XW
  k_mega<<<(Bsz * Nn) / 32, 512, 0, stream>>>(bits, YtA, W2, dinv, b1, YtB,
                                              KEY1.a, KEY1.b);
  // layer 2 aggregate + epilogue + layer 3 XW
  k_mega<<<(Bsz * Nn) / 32, 512, 0, stream>>>(bits, YtB, W3, dinv, b2, YtA,
                                              KEY2.a, KEY2.b);
  // layer 3 aggregate + bias -> out
  k_fin<<<(Bsz * Nn) / 32, 512, 0, stream>>>(bits, YtA, dinv, b3, out);
}